// Round 2
// baseline (771.296 us; speedup 1.0000x reference)
//
#include <hip/hip_runtime.h>
#include <cstdint>
#include <cmath>

// Binarized MLP via i8 MFMA: 16384x1024 -> 2048 -> 2048 -> 2048 -> 2.
// Activations/weights are exactly {-1,+1} -> i8; matmuls use
// mfma_i32_16x16x64_i8 with exact i32 accumulation. BN+binq folds to
// per-neuron float threshold: next_act = (alpha*c + beta >= 0) ? +1 : -1.

typedef int i32x4 __attribute__((ext_vector_type(4)));

static constexpr int THREADS = 256;
static constexpr int Bsz = 16384;
static constexpr int Din = 1024;
static constexpr int Hid = 2048;

// ---------------- float -> i8 sign (+1/-1), float4 vectorized --------------
__global__ void sign_kernel(const float* __restrict__ src, char* __restrict__ dst,
                            int n4, float thr) {
  int i = blockIdx.x * THREADS + threadIdx.x;
  if (i < n4) {
    float4 v = ((const float4*)src)[i];
    char4 o;
    o.x = (v.x >= thr) ? 1 : -1;
    o.y = (v.y >= thr) ? 1 : -1;
    o.z = (v.z >= thr) ? 1 : -1;
    o.w = (v.w >= thr) ? 1 : -1;
    ((char4*)dst)[i] = o;
  }
}

// ---------------- fold BN into (alpha, beta) per neuron --------------------
__global__ void bnprep_kernel(const float* __restrict__ g, const float* __restrict__ b,
                              const float* __restrict__ m, const float* __restrict__ v,
                              float* __restrict__ alpha, float* __restrict__ beta, int n) {
  int i = blockIdx.x * THREADS + threadIdx.x;
  if (i < n) {
    float a = g[i] / sqrtf(v[i] + 1e-5f);
    alpha[i] = a;
    beta[i] = b[i] - m[i] * a;
  }
}

// ---------------- i8 MFMA layer: C = A x W^T, BN-threshold, emit i8 --------
// Block 128(m) x 128(n), 4 waves in 2x2; wave tile 64x64 = 4x4 mfma tiles.
// A [M][K] i8 row-major, W [N][K] i8 row-major. K in {1024, 2048}.
// Frag layout (16x16x64): lane&15 = row, lane>>4 = k-quad, 16 bytes/lane.
template <int K>
__global__ __launch_bounds__(256, 3) void layer_mfma(
    const char* __restrict__ A, const char* __restrict__ W,
    const float* __restrict__ alpha, const float* __restrict__ beta,
    char* __restrict__ O) {
  constexpr int N = Hid;
  constexpr int K64 = K / 64;
  const int tid = threadIdx.x;
  const int wave = tid >> 6, lane = tid & 63;
  const int m0 = blockIdx.x * 128 + (wave >> 1) * 64;
  const int n0 = blockIdx.y * 128 + (wave & 1) * 64;
  const int lr = lane & 15, lk = lane >> 4;

  const char* aP = A + (size_t)(m0 + lr) * K + lk * 16;
  const char* bP = W + (size_t)(n0 + lr) * K + lk * 16;

  i32x4 acc[4][4] = {};
  i32x4 aF[2][4], bF[2][4];

#define LD_FRAGS(buf, kk)                                                  \
  {                                                                        \
    _Pragma("unroll") for (int t = 0; t < 4; ++t) {                        \
      aF[buf][t] = *(const i32x4*)(aP + (size_t)t * 16 * K + (kk) * 64);   \
      bF[buf][t] = *(const i32x4*)(bP + (size_t)t * 16 * K + (kk) * 64);   \
    }                                                                      \
  }
#define DO_MFMA(buf)                                                       \
  {                                                                        \
    _Pragma("unroll") for (int mt = 0; mt < 4; ++mt)                       \
        _Pragma("unroll") for (int nt = 0; nt < 4; ++nt)                   \
            acc[mt][nt] = __builtin_amdgcn_mfma_i32_16x16x64_i8(           \
                aF[buf][mt], bF[buf][nt], acc[mt][nt], 0, 0, 0);           \
  }

  LD_FRAGS(0, 0);
  for (int kk = 0; kk < K64; kk += 2) {
    LD_FRAGS(1, kk + 1);
    DO_MFMA(0);
    if (kk + 2 < K64) LD_FRAGS(0, kk + 2);
    DO_MFMA(1);
  }
#undef LD_FRAGS
#undef DO_MFMA

  float al[4], be[4];
#pragma unroll
  for (int nt = 0; nt < 4; ++nt) {
    int n = n0 + nt * 16 + lr;
    al[nt] = alpha[n];
    be[nt] = beta[n];
  }
#pragma unroll
  for (int mt = 0; mt < 4; ++mt)
#pragma unroll
    for (int r = 0; r < 4; ++r) {
      int m = m0 + mt * 16 + lk * 4 + r;   // C/D: row = (lane>>4)*4 + reg
      char* orow = O + (size_t)m * N;
#pragma unroll
      for (int nt = 0; nt < 4; ++nt) {
        float c = (float)acc[mt][nt][r];
        orow[n0 + nt * 16 + lr] = (fmaf(al[nt], c, be[nt]) >= 0.0f) ? 1 : -1;
      }
    }
}

// ---------------- final 2-neuron layer: wave per row, exact ints -----------
__global__ void final_kernel(const char* __restrict__ A,   // [B][2048] i8
                             const char* __restrict__ Ws,  // [2][2048] i8
                             float* __restrict__ out, int B) {
  int row = blockIdx.x * 4 + (threadIdx.x >> 6);
  int lane = threadIdx.x & 63;
  if (row >= B) return;
  const char* a = A + (size_t)row * 2048 + lane * 32;
  const char* w0 = Ws + lane * 32;
  const char* w1 = Ws + 2048 + lane * 32;

  union U { i32x4 v; signed char c[16]; };
  int s0 = 0, s1 = 0;
#pragma unroll
  for (int h = 0; h < 2; ++h) {
    U ua, u0, u1;
    ua.v = *(const i32x4*)(a + h * 16);
    u0.v = *(const i32x4*)(w0 + h * 16);
    u1.v = *(const i32x4*)(w1 + h * 16);
#pragma unroll
    for (int i = 0; i < 16; ++i) {
      int av = ua.c[i];
      s0 += av * (int)u0.c[i];
      s1 += av * (int)u1.c[i];
    }
  }
#pragma unroll
  for (int off = 32; off; off >>= 1) {
    s0 += __shfl_xor(s0, off, 64);
    s1 += __shfl_xor(s1, off, 64);
  }
  if (lane == 0) {
    out[row * 2 + 0] = (float)s0;
    out[row * 2 + 1] = (float)s1;
  }
}

extern "C" void kernel_launch(void* const* d_in, const int* in_sizes, int n_in,
                              void* d_out, int out_size, void* d_ws, size_t ws_size,
                              hipStream_t stream) {
  const float* x    = (const float*)d_in[0];
  const float* w1   = (const float*)d_in[1];
  const float* g1   = (const float*)d_in[2];
  const float* b1   = (const float*)d_in[3];
  const float* m1   = (const float*)d_in[4];
  const float* v1   = (const float*)d_in[5];
  const float* w2   = (const float*)d_in[6];
  const float* g2   = (const float*)d_in[7];
  const float* b2   = (const float*)d_in[8];
  const float* m2   = (const float*)d_in[9];
  const float* v2   = (const float*)d_in[10];
  const float* w3   = (const float*)d_in[11];
  const float* g3   = (const float*)d_in[12];
  const float* b3   = (const float*)d_in[13];
  const float* m3   = (const float*)d_in[14];
  const float* v3   = (const float*)d_in[15];
  const float* wout = (const float*)d_in[16];
  float* out = (float*)d_out;

  char* base = (char*)d_ws;
  size_t off = 0;
  auto take = [&](size_t bytes) -> char* {
    char* p = base + off;
    off += (bytes + 255) & ~(size_t)255;
    return p;
  };
  char* A0  = take((size_t)Bsz * Din);   // 16.8 MB i8
  char* Aa  = take((size_t)Bsz * Hid);   // 33.5 MB
  char* Ab  = take((size_t)Bsz * Hid);   // 33.5 MB
  char* W1s = take((size_t)Hid * Din);
  char* W2s = take((size_t)Hid * Hid);
  char* W3s = take((size_t)Hid * Hid);
  char* Wos = take(2 * Hid);
  float* a1 = (float*)take(Hid * 4);
  float* be1 = (float*)take(Hid * 4);
  float* a2 = (float*)take(Hid * 4);
  float* be2 = (float*)take(Hid * 4);
  float* a3 = (float*)take(Hid * 4);
  float* be3 = (float*)take(Hid * 4);

  auto blocks = [](int n) { return (n + THREADS - 1) / THREADS; };

  // binq(2x-1) >= 0  <=>  x >= 0.5 ; weights threshold at 0
  sign_kernel<<<blocks(Bsz * Din / 4), THREADS, 0, stream>>>(x, A0, Bsz * Din / 4, 0.5f);
  sign_kernel<<<blocks(Hid * Din / 4), THREADS, 0, stream>>>(w1, W1s, Hid * Din / 4, 0.0f);
  sign_kernel<<<blocks(Hid * Hid / 4), THREADS, 0, stream>>>(w2, W2s, Hid * Hid / 4, 0.0f);
  sign_kernel<<<blocks(Hid * Hid / 4), THREADS, 0, stream>>>(w3, W3s, Hid * Hid / 4, 0.0f);
  sign_kernel<<<blocks(2 * Hid / 4), THREADS, 0, stream>>>(wout, Wos, 2 * Hid / 4, 0.0f);

  bnprep_kernel<<<blocks(Hid), THREADS, 0, stream>>>(g1, b1, m1, v1, a1, be1, Hid);
  bnprep_kernel<<<blocks(Hid), THREADS, 0, stream>>>(g2, b2, m2, v2, a2, be2, Hid);
  bnprep_kernel<<<blocks(Hid), THREADS, 0, stream>>>(g3, b3, m3, v3, a3, be3, Hid);

  // blockIdx.x = M-dim (fastest) so co-resident blocks share the B(N)-panel
  dim3 lgrid(Bsz / 128, Hid / 128);
  layer_mfma<Din><<<lgrid, THREADS, 0, stream>>>(A0, W1s, a1, be1, Aa);
  layer_mfma<Hid><<<lgrid, THREADS, 0, stream>>>(Aa, W2s, a2, be2, Ab);
  layer_mfma<Hid><<<lgrid, THREADS, 0, stream>>>(Ab, W3s, a3, be3, Aa);

  final_kernel<<<Bsz / 4, THREADS, 0, stream>>>(Aa, Wos, out, Bsz);
}

// Round 3
// 334.558 us; speedup vs baseline: 2.3054x; 2.3054x over previous
//
#include <hip/hip_runtime.h>
#include <cstdint>
#include <cmath>

// Binarized MLP via i8 MFMA: 16384x1024 -> 2048 -> 2048 -> 2048 -> 2.
// Acts/weights are exactly {-1,+1} as i8; mfma_i32_16x16x64_i8 gives exact
// i32 accumulation. BN+binq folds to per-neuron float threshold.
// Layer GEMM: canonical LDS double-buffered structure with
// global_load_lds(width=16); global-source XOR swizzle (chunk ^= row&7)
// keeps fragment ds_read_b128 at 2-way bank aliasing (free).

typedef int i32x4 __attribute__((ext_vector_type(4)));

static constexpr int THREADS = 256;
static constexpr int Bsz = 16384;
static constexpr int Din = 1024;
static constexpr int Hid = 2048;

__device__ __forceinline__ void ld16(const void* g, void* l) {
  __builtin_amdgcn_global_load_lds(
      (const __attribute__((address_space(1))) void*)g,
      (__attribute__((address_space(3))) void*)l, 16, 0, 0);
}

// ---------------- float -> i8 sign (+1/-1), float4 vectorized --------------
__global__ void sign_kernel(const float* __restrict__ src, char* __restrict__ dst,
                            int n4, float thr) {
  int i = blockIdx.x * THREADS + threadIdx.x;
  if (i < n4) {
    float4 v = ((const float4*)src)[i];
    char4 o;
    o.x = (v.x >= thr) ? 1 : -1;
    o.y = (v.y >= thr) ? 1 : -1;
    o.z = (v.z >= thr) ? 1 : -1;
    o.w = (v.w >= thr) ? 1 : -1;
    ((char4*)dst)[i] = o;
  }
}

// ---------------- fold BN into (alpha, beta) per neuron --------------------
__global__ void bnprep_kernel(const float* __restrict__ g, const float* __restrict__ b,
                              const float* __restrict__ m, const float* __restrict__ v,
                              float* __restrict__ alpha, float* __restrict__ beta, int n) {
  int i = blockIdx.x * THREADS + threadIdx.x;
  if (i < n) {
    float a = g[i] / sqrtf(v[i] + 1e-5f);
    alpha[i] = a;
    beta[i] = b[i] - m[i] * a;
  }
}

// ---------------- i8 MFMA layer: C = A x W^T, BN-threshold, emit i8 --------
// Block 128(m) x 128(n) x 128(k bytes) per stage; 4 waves 2x2, wave 64x64.
// A [M][K], W [N][K] row-major i8. LDS: [2 bufs][A 16KB | B 16KB] = 64 KB.
// LDS A/B tile layout: row-major 128 rows x 128 B, but the 16-B chunk index
// within a row is XOR-swizzled by (row&7) at staging time (global side).
template <int K>
__global__ __launch_bounds__(256, 2) void layer_mfma(
    const char* __restrict__ A, const char* __restrict__ W,
    const float* __restrict__ alpha, const float* __restrict__ beta,
    char* __restrict__ O) {
  constexpr int N = Hid;
  constexpr int S = K / 128;                  // k stages
  __shared__ __align__(16) char lds[2][32768];

  const int tid = threadIdx.x;
  const int wave = tid >> 6, lane = tid & 63;
  const int n0 = blockIdx.x * 128;
  const int m0 = blockIdx.y * 128;

  // ---- staging setup: this wave's 8 chunks (1 KB each, lane L -> +L*16) ---
  const char* gp[8];
  int loff[8];
#pragma unroll
  for (int ci = 0; ci < 8; ++ci) {
    int c = wave * 8 + ci;                    // 0..15 A-tile, 16..31 B-tile
    bool isA = c < 16;
    int cc = isA ? c : c - 16;
    int row = cc * 8 + (lane >> 3);           // local row 0..127
    int sub = lane & 7;                       // physical 16B slot in row
    int kc = sub ^ (row & 7);                 // logical k-chunk (swizzle)
    const char* base = isA ? (A + (size_t)(m0 + row) * K)
                           : (W + (size_t)(n0 + row) * K);
    gp[ci] = base + kc * 16;
    loff[ci] = (isA ? 0 : 16384) + cc * 1024;
  }

  // ---- fragment read offsets --------------------------------------------
  const int lr = lane & 15, lk = lane >> 4;
  const int rA = ((wave >> 1) << 6) + lr;     // local A row (+ mt*16)
  const int rB = ((wave & 1) << 6) + lr;      // local B row (+ nt*16)
  int aoff[2], boff[2];
#pragma unroll
  for (int s = 0; s < 2; ++s) {
    aoff[s] = rA * 128 + ((s * 4 + lk) ^ (lr & 7)) * 16;
    boff[s] = 16384 + rB * 128 + ((s * 4 + lk) ^ (lr & 7)) * 16;
  }

  i32x4 acc[4][4] = {};

  // ---- prologue: stage 0 ------------------------------------------------
#pragma unroll
  for (int ci = 0; ci < 8; ++ci) ld16(gp[ci], &lds[0][loff[ci]]);
#pragma unroll
  for (int ci = 0; ci < 8; ++ci) gp[ci] += 128;
  __syncthreads();

  int buf = 0;
  for (int ks = 0; ks < S; ++ks) {
    if (ks + 1 < S) {
#pragma unroll
      for (int ci = 0; ci < 8; ++ci) ld16(gp[ci], &lds[buf ^ 1][loff[ci]]);
#pragma unroll
      for (int ci = 0; ci < 8; ++ci) gp[ci] += 128;
    }
    const char* lb = &lds[buf][0];
#pragma unroll
    for (int s = 0; s < 2; ++s) {
      i32x4 aF[4], bF[4];
#pragma unroll
      for (int t = 0; t < 4; ++t) {
        aF[t] = *(const i32x4*)(lb + aoff[s] + t * 2048);
        bF[t] = *(const i32x4*)(lb + boff[s] + t * 2048);
      }
#pragma unroll
      for (int mt = 0; mt < 4; ++mt)
#pragma unroll
        for (int nt = 0; nt < 4; ++nt)
          acc[mt][nt] = __builtin_amdgcn_mfma_i32_16x16x64_i8(
              aF[mt], bF[nt], acc[mt][nt], 0, 0, 0);
    }
    __syncthreads();   // drains next-stage DMA (vmcnt0) + protects buf reuse
    buf ^= 1;
  }

  // ---- epilogue: BN threshold, emit i8 ----------------------------------
  float al[4], be[4];
#pragma unroll
  for (int nt = 0; nt < 4; ++nt) {
    int n = n0 + ((wave & 1) << 6) + nt * 16 + lr;
    al[nt] = alpha[n];
    be[nt] = beta[n];
  }
#pragma unroll
  for (int mt = 0; mt < 4; ++mt)
#pragma unroll
    for (int r = 0; r < 4; ++r) {
      int m = m0 + ((wave >> 1) << 6) + mt * 16 + lk * 4 + r;
      char* orow = O + (size_t)m * N;
#pragma unroll
      for (int nt = 0; nt < 4; ++nt) {
        float c = (float)acc[mt][nt][r];
        orow[n0 + ((wave & 1) << 6) + nt * 16 + lr] =
            (fmaf(al[nt], c, be[nt]) >= 0.0f) ? 1 : -1;
      }
    }
}

// ---------------- final 2-neuron layer: wave per row, exact ints -----------
__global__ void final_kernel(const char* __restrict__ A,   // [B][2048] i8
                             const char* __restrict__ Ws,  // [2][2048] i8
                             float* __restrict__ out, int B) {
  int row = blockIdx.x * 4 + (threadIdx.x >> 6);
  int lane = threadIdx.x & 63;
  if (row >= B) return;
  const char* a = A + (size_t)row * 2048 + lane * 32;
  const char* w0 = Ws + lane * 32;
  const char* w1 = Ws + 2048 + lane * 32;

  union U { i32x4 v; signed char c[16]; };
  int s0 = 0, s1 = 0;
#pragma unroll
  for (int h = 0; h < 2; ++h) {
    U ua, u0, u1;
    ua.v = *(const i32x4*)(a + h * 16);
    u0.v = *(const i32x4*)(w0 + h * 16);
    u1.v = *(const i32x4*)(w1 + h * 16);
#pragma unroll
    for (int i = 0; i < 16; ++i) {
      int av = ua.c[i];
      s0 += av * (int)u0.c[i];
      s1 += av * (int)u1.c[i];
    }
  }
#pragma unroll
  for (int off = 32; off; off >>= 1) {
    s0 += __shfl_xor(s0, off, 64);
    s1 += __shfl_xor(s1, off, 64);
  }
  if (lane == 0) {
    out[row * 2 + 0] = (float)s0;
    out[row * 2 + 1] = (float)s1;
  }
}

extern "C" void kernel_launch(void* const* d_in, const int* in_sizes, int n_in,
                              void* d_out, int out_size, void* d_ws, size_t ws_size,
                              hipStream_t stream) {
  const float* x    = (const float*)d_in[0];
  const float* w1   = (const float*)d_in[1];
  const float* g1   = (const float*)d_in[2];
  const float* b1   = (const float*)d_in[3];
  const float* m1   = (const float*)d_in[4];
  const float* v1   = (const float*)d_in[5];
  const float* w2   = (const float*)d_in[6];
  const float* g2   = (const float*)d_in[7];
  const float* b2   = (const float*)d_in[8];
  const float* m2   = (const float*)d_in[9];
  const float* v2   = (const float*)d_in[10];
  const float* w3   = (const float*)d_in[11];
  const float* g3   = (const float*)d_in[12];
  const float* b3   = (const float*)d_in[13];
  const float* m3   = (const float*)d_in[14];
  const float* v3   = (const float*)d_in[15];
  const float* wout = (const float*)d_in[16];
  float* out = (float*)d_out;

  char* base = (char*)d_ws;
  size_t off = 0;
  auto take = [&](size_t bytes) -> char* {
    char* p = base + off;
    off += (bytes + 255) & ~(size_t)255;
    return p;
  };
  char* A0  = take((size_t)Bsz * Din);
  char* Aa  = take((size_t)Bsz * Hid);
  char* Ab  = take((size_t)Bsz * Hid);
  char* W1s = take((size_t)Hid * Din);
  char* W2s = take((size_t)Hid * Hid);
  char* W3s = take((size_t)Hid * Hid);
  char* Wos = take(2 * Hid);
  float* a1 = (float*)take(Hid * 4);
  float* be1 = (float*)take(Hid * 4);
  float* a2 = (float*)take(Hid * 4);
  float* be2 = (float*)take(Hid * 4);
  float* a3 = (float*)take(Hid * 4);
  float* be3 = (float*)take(Hid * 4);

  auto blocks = [](int n) { return (n + THREADS - 1) / THREADS; };

  // binq(2x-1) >= 0  <=>  x >= 0.5 ; weights threshold at 0
  sign_kernel<<<blocks(Bsz * Din / 4), THREADS, 0, stream>>>(x, A0, Bsz * Din / 4, 0.5f);
  sign_kernel<<<blocks(Hid * Din / 4), THREADS, 0, stream>>>(w1, W1s, Hid * Din / 4, 0.0f);
  sign_kernel<<<blocks(Hid * Hid / 4), THREADS, 0, stream>>>(w2, W2s, Hid * Hid / 4, 0.0f);
  sign_kernel<<<blocks(Hid * Hid / 4), THREADS, 0, stream>>>(w3, W3s, Hid * Hid / 4, 0.0f);
  sign_kernel<<<blocks(2 * Hid / 4), THREADS, 0, stream>>>(wout, Wos, 2 * Hid / 4, 0.0f);

  bnprep_kernel<<<blocks(Hid), THREADS, 0, stream>>>(g1, b1, m1, v1, a1, be1, Hid);
  bnprep_kernel<<<blocks(Hid), THREADS, 0, stream>>>(g2, b2, m2, v2, a2, be2, Hid);
  bnprep_kernel<<<blocks(Hid), THREADS, 0, stream>>>(g3, b3, m3, v3, a3, be3, Hid);

  // x = N (16 blocks, fastest) so co-resident blocks share the A-panel in L2
  dim3 lgrid(Hid / 128, Bsz / 128);
  layer_mfma<Din><<<lgrid, THREADS, 0, stream>>>(A0, W1s, a1, be1, Aa);
  layer_mfma<Hid><<<lgrid, THREADS, 0, stream>>>(Aa, W2s, a2, be2, Ab);
  layer_mfma<Hid><<<lgrid, THREADS, 0, stream>>>(Ab, W3s, a3, be3, Aa);

  final_kernel<<<Bsz / 4, THREADS, 0, stream>>>(Aa, Wos, out, Bsz);
}

// Round 4
// 326.120 us; speedup vs baseline: 2.3651x; 1.0259x over previous
//
#include <hip/hip_runtime.h>
#include <cstdint>
#include <cmath>

// Binarized MLP via i8 MFMA: 16384x1024 -> 2048 -> 2048 -> 2048 -> 2.
// Acts/weights are exactly {-1,+1} as i8; mfma_i32_16x16x64_i8 gives exact
// i32 accumulation. BN+binq folds to per-neuron float threshold.
// R4: 256x128 block tile (8 waves, single-buffered 48KB LDS, 2 blocks/CU
// cross-block overlap), XCD-aware block swizzle (8 m-panels per XCD ->
// ~512KB hot k-slice per XCD L2), fused prep (5 sign/bnprep kernels -> 1),
// final 2-neuron layer fused into layer-3 epilogue via exact f32 atomics.

typedef int i32x4 __attribute__((ext_vector_type(4)));

static constexpr int Bsz = 16384;
static constexpr int Din = 1024;
static constexpr int Hid = 2048;

__device__ __forceinline__ void ld16(const void* g, void* l) {
  __builtin_amdgcn_global_load_lds(
      (const __attribute__((address_space(1))) void*)g,
      (__attribute__((address_space(3))) void*)l, 16, 0, 0);
}

// ---------------- fused prep: all sign-quantizations + BN folds ------------
// blocks [0,16384): x -> A0 (thr 0.5; binq(2x-1)>=0 <=> x>=0.5)
// blocks [16384,18432): w1 -> W1s   [18432,22528): w2 -> W2s
// blocks [22528,26624): w3 -> W3s   [26624,26648): bnprep for 3 layers
__global__ void prep_kernel(
    const float* __restrict__ x, const float* __restrict__ w1,
    const float* __restrict__ w2, const float* __restrict__ w3,
    const float* __restrict__ g1, const float* __restrict__ b1,
    const float* __restrict__ m1, const float* __restrict__ v1,
    const float* __restrict__ g2, const float* __restrict__ b2,
    const float* __restrict__ m2, const float* __restrict__ v2,
    const float* __restrict__ g3, const float* __restrict__ b3,
    const float* __restrict__ m3, const float* __restrict__ v3,
    char* __restrict__ A0, char* __restrict__ W1s,
    char* __restrict__ W2s, char* __restrict__ W3s,
    float* __restrict__ a1, float* __restrict__ be1,
    float* __restrict__ a2, float* __restrict__ be2,
    float* __restrict__ a3, float* __restrict__ be3) {
  constexpr int BX = 16384, BW1 = 2048, BW2 = 4096, BW3 = 4096;
  const int blk = blockIdx.x;
  if (blk < BX + BW1 + BW2 + BW3) {
    const float* s;
    char* d;
    float thr = 0.0f;
    int rb;
    if (blk < BX) {
      s = x; d = A0; thr = 0.5f; rb = 0;
    } else if (blk < BX + BW1) {
      s = w1; d = W1s; rb = BX;
    } else if (blk < BX + BW1 + BW2) {
      s = w2; d = W2s; rb = BX + BW1;
    } else {
      s = w3; d = W3s; rb = BX + BW1 + BW2;
    }
    int i = (blk - rb) * 256 + threadIdx.x;
    float4 v = ((const float4*)s)[i];
    char4 o;
    o.x = (v.x >= thr) ? 1 : -1;
    o.y = (v.y >= thr) ? 1 : -1;
    o.z = (v.z >= thr) ? 1 : -1;
    o.w = (v.w >= thr) ? 1 : -1;
    ((char4*)d)[i] = o;
  } else {
    int t = (blk - (BX + BW1 + BW2 + BW3)) * 256 + threadIdx.x;  // 0..6143
    int l = t >> 11, e = t & 2047;
    const float *g, *b, *m, *v;
    float *al, *be;
    if (l == 0) { g = g1; b = b1; m = m1; v = v1; al = a1; be = be1; }
    else if (l == 1) { g = g2; b = b2; m = m2; v = v2; al = a2; be = be2; }
    else { g = g3; b = b3; m = m3; v = v3; al = a3; be = be3; }
    float a = g[e] / sqrtf(v[e] + 1e-5f);
    al[e] = a;
    be[e] = b[e] - m[e] * a;
  }
}

// ---------------- i8 MFMA layer: C = A x W^T ------------------------------
// Block 256(m) x 128(n) x BK=128 bytes, single-buffered LDS (48 KB).
// 8 waves as 4(m) x 2(n); wave tile 64x64 = 4x4 mfma 16x16x64 tiles.
// LDS rows of 128B, 16B-chunk XOR-swizzled by (row&7) at global source.
// FINAL: instead of writing i8, dot with sign(wout) rows and atomicAdd
// exact-integer partials into out[m][2] (f32, |sum|<=2048 -> exact).
template <int K, bool FINAL>
__global__ __launch_bounds__(512, 4) void layer_mfma(
    const char* __restrict__ A, const char* __restrict__ W,
    const float* __restrict__ alpha, const float* __restrict__ beta,
    char* __restrict__ O, const float* __restrict__ wout,
    float* __restrict__ out) {
  constexpr int N = Hid;
  constexpr int S = K / 128;
  __shared__ __align__(16) char lds[49152];  // A 32KB | B 16KB

  const int tid = threadIdx.x;
  const int wave = tid >> 6, lane = tid & 63;

  // XCD swizzle: xcd = id&7 owns m-panels [xcd*8, xcd*8+8)
  const int id = blockIdx.x;
  const int mp = (id & 7) * 8 + ((id >> 3) & 7);
  const int np = id >> 6;
  const int m0 = mp * 256, n0 = np * 128;

  // staging: 48 chunks of 1KB (A:0..31 rows 256x128B, B:32..47 rows 128x128B)
  const char* gp[6];
  char* lp[6];
#pragma unroll
  for (int ci = 0; ci < 6; ++ci) {
    int c = wave * 6 + ci;
    bool isA = c < 32;
    int cc = isA ? c : c - 32;
    int row = cc * 8 + (lane >> 3);
    int kc = (lane & 7) ^ (row & 7);  // logical k-chunk at physical slot
    gp[ci] = (isA ? A + (size_t)(m0 + row) * K
                  : W + (size_t)(n0 + row) * K) + kc * 16;
    lp[ci] = &lds[(isA ? 0 : 32768) + cc * 1024];
  }

  const int lr = lane & 15, lk = lane >> 4;
  const int wm = wave >> 1, wn = wave & 1;
  int aofs[2], bofs[2];
#pragma unroll
  for (int s = 0; s < 2; ++s) {
    aofs[s] = (wm * 64 + lr) * 128 + ((s * 4 + lk) ^ (lr & 7)) * 16;
    bofs[s] = 32768 + (wn * 64 + lr) * 128 + ((s * 4 + lk) ^ (lr & 7)) * 16;
  }

  i32x4 acc[4][4] = {};

  for (int ks = 0; ks < S; ++ks) {
#pragma unroll
    for (int ci = 0; ci < 6; ++ci) {
      ld16(gp[ci], lp[ci]);
      gp[ci] += 128;
    }
    __syncthreads();  // drains DMA (vmcnt0 before barrier)
#pragma unroll
    for (int s = 0; s < 2; ++s) {
      i32x4 aF[4], bF[4];
#pragma unroll
      for (int t = 0; t < 4; ++t) {
        aF[t] = *(const i32x4*)(lds + aofs[s] + t * 2048);
        bF[t] = *(const i32x4*)(lds + bofs[s] + t * 2048);
      }
#pragma unroll
      for (int mt = 0; mt < 4; ++mt)
#pragma unroll
        for (int nt = 0; nt < 4; ++nt)
          acc[mt][nt] = __builtin_amdgcn_mfma_i32_16x16x64_i8(
              aF[mt], bF[nt], acc[mt][nt], 0, 0, 0);
    }
    __syncthreads();  // protect single buffer before next stage's DMA
  }

  float al[4], be[4];
#pragma unroll
  for (int nt = 0; nt < 4; ++nt) {
    int n = n0 + wn * 64 + nt * 16 + lr;
    al[nt] = alpha[n];
    be[nt] = beta[n];
  }

  if (!FINAL) {
#pragma unroll
    for (int mt = 0; mt < 4; ++mt)
#pragma unroll
      for (int r = 0; r < 4; ++r) {
        int m = m0 + wm * 64 + mt * 16 + lk * 4 + r;  // C/D row=(lane>>4)*4+reg
        char* orow = O + (size_t)m * N;
#pragma unroll
        for (int nt = 0; nt < 4; ++nt) {
          float c = (float)acc[mt][nt][r];
          orow[n0 + wn * 64 + nt * 16 + lr] =
              (fmaf(al[nt], c, be[nt]) >= 0.0f) ? 1 : -1;
        }
      }
  } else {
    int ws0[4], ws1[4];
#pragma unroll
    for (int nt = 0; nt < 4; ++nt) {
      int n = n0 + wn * 64 + nt * 16 + lr;
      ws0[nt] = (wout[n] >= 0.0f) ? 1 : -1;
      ws1[nt] = (wout[2048 + n] >= 0.0f) ? 1 : -1;
    }
#pragma unroll
    for (int mt = 0; mt < 4; ++mt)
#pragma unroll
      for (int r = 0; r < 4; ++r) {
        int m = m0 + wm * 64 + mt * 16 + lk * 4 + r;
        int p0 = 0, p1 = 0;
#pragma unroll
        for (int nt = 0; nt < 4; ++nt) {
          float c = (float)acc[mt][nt][r];
          int a = (fmaf(al[nt], c, be[nt]) >= 0.0f) ? 1 : -1;
          p0 += a * ws0[nt];
          p1 += a * ws1[nt];
        }
        // reduce across lr (lane bits 0..3)
#pragma unroll
        for (int off = 1; off <= 8; off <<= 1) {
          p0 += __shfl_xor(p0, off, 64);
          p1 += __shfl_xor(p1, off, 64);
        }
        if (lr == 0) {
          atomicAdd(&out[m * 2 + 0], (float)p0);
          atomicAdd(&out[m * 2 + 1], (float)p1);
        }
      }
  }
}

extern "C" void kernel_launch(void* const* d_in, const int* in_sizes, int n_in,
                              void* d_out, int out_size, void* d_ws, size_t ws_size,
                              hipStream_t stream) {
  const float* x    = (const float*)d_in[0];
  const float* w1   = (const float*)d_in[1];
  const float* g1   = (const float*)d_in[2];
  const float* b1   = (const float*)d_in[3];
  const float* m1   = (const float*)d_in[4];
  const float* v1   = (const float*)d_in[5];
  const float* w2   = (const float*)d_in[6];
  const float* g2   = (const float*)d_in[7];
  const float* b2   = (const float*)d_in[8];
  const float* m2   = (const float*)d_in[9];
  const float* v2   = (const float*)d_in[10];
  const float* w3   = (const float*)d_in[11];
  const float* g3   = (const float*)d_in[12];
  const float* b3   = (const float*)d_in[13];
  const float* m3   = (const float*)d_in[14];
  const float* v3   = (const float*)d_in[15];
  const float* wout = (const float*)d_in[16];
  float* out = (float*)d_out;

  char* base = (char*)d_ws;
  size_t off = 0;
  auto take = [&](size_t bytes) -> char* {
    char* p = base + off;
    off += (bytes + 255) & ~(size_t)255;
    return p;
  };
  char* A0  = take((size_t)Bsz * Din);
  char* Aa  = take((size_t)Bsz * Hid);
  char* Ab  = take((size_t)Bsz * Hid);
  char* W1s = take((size_t)Hid * Din);
  char* W2s = take((size_t)Hid * Hid);
  char* W3s = take((size_t)Hid * Hid);
  float* a1  = (float*)take(Hid * 4);
  float* be1 = (float*)take(Hid * 4);
  float* a2  = (float*)take(Hid * 4);
  float* be2 = (float*)take(Hid * 4);
  float* a3  = (float*)take(Hid * 4);
  float* be3 = (float*)take(Hid * 4);

  hipMemsetAsync(d_out, 0, (size_t)out_size * sizeof(float), stream);

  prep_kernel<<<26648, 256, 0, stream>>>(
      x, w1, w2, w3,
      g1, b1, m1, v1, g2, b2, m2, v2, g3, b3, m3, v3,
      A0, W1s, W2s, W3s, a1, be1, a2, be2, a3, be3);

  // grid 1024: (16384/256) m-panels x (2048/128) n-panels, XCD-swizzled
  layer_mfma<Din, false><<<1024, 512, 0, stream>>>(A0, W1s, a1, be1, Aa,
                                                   nullptr, nullptr);
  layer_mfma<Hid, false><<<1024, 512, 0, stream>>>(Aa, W2s, a2, be2, Ab,
                                                   nullptr, nullptr);
  layer_mfma<Hid, true><<<1024, 512, 0, stream>>>(Ab, W3s, a3, be3, nullptr,
                                                  wout, out);
}